// Round 1
// baseline (733.154 us; speedup 1.0000x reference)
//
#include <hip/hip_runtime.h>

#define NTOK 4096
#define EPS 1e-5f

// ---------------- K0: zero the stats accumulators ----------------
__global__ void k_zero(float* __restrict__ stats) {
    int t = blockIdx.x * blockDim.x + threadIdx.x;
    if (t < 1024) stats[t] = 0.0f;
}

// ---------------- K1: q = x @ Wq^T  (M=4096,N=512,K=512, all row-major K-contiguous)
__global__ __launch_bounds__(256) void k_gemm(const float* __restrict__ A,
                                              const float* __restrict__ B,
                                              float* __restrict__ C) {
    __shared__ float As[32][68];   // transposed: As[k][row]
    __shared__ float Bs[32][68];
    const int tid  = threadIdx.x;
    const int row0 = blockIdx.x * 64;
    const int col0 = blockIdx.y * 64;
    const int lr = tid >> 3;          // 0..31
    const int lc = (tid & 7) << 2;    // 0,4,...,28
    const int tx = tid & 15;
    const int ty = tid >> 4;
    float acc[4][4] = {};
    for (int kc = 0; kc < 512; kc += 32) {
        float4 a0 = *(const float4*)(A + (row0 + lr)      * 512 + kc + lc);
        float4 a1 = *(const float4*)(A + (row0 + lr + 32) * 512 + kc + lc);
        float4 b0 = *(const float4*)(B + (col0 + lr)      * 512 + kc + lc);
        float4 b1 = *(const float4*)(B + (col0 + lr + 32) * 512 + kc + lc);
        __syncthreads();
        As[lc + 0][lr] = a0.x; As[lc + 1][lr] = a0.y; As[lc + 2][lr] = a0.z; As[lc + 3][lr] = a0.w;
        As[lc + 0][lr + 32] = a1.x; As[lc + 1][lr + 32] = a1.y; As[lc + 2][lr + 32] = a1.z; As[lc + 3][lr + 32] = a1.w;
        Bs[lc + 0][lr] = b0.x; Bs[lc + 1][lr] = b0.y; Bs[lc + 2][lr] = b0.z; Bs[lc + 3][lr] = b0.w;
        Bs[lc + 0][lr + 32] = b1.x; Bs[lc + 1][lr + 32] = b1.y; Bs[lc + 2][lr + 32] = b1.z; Bs[lc + 3][lr + 32] = b1.w;
        __syncthreads();
        #pragma unroll
        for (int k = 0; k < 32; ++k) {
            const float4 av = *(const float4*)&As[k][ty << 2];
            const float4 bv = *(const float4*)&Bs[k][tx << 2];
            const float a[4] = {av.x, av.y, av.z, av.w};
            const float b[4] = {bv.x, bv.y, bv.z, bv.w};
            #pragma unroll
            for (int i = 0; i < 4; ++i)
                #pragma unroll
                for (int j = 0; j < 4; ++j)
                    acc[i][j] += a[i] * b[j];
        }
    }
    #pragma unroll
    for (int i = 0; i < 4; ++i) {
        float4 v = make_float4(acc[i][0], acc[i][1], acc[i][2], acc[i][3]);
        *(float4*)(C + (row0 + ty * 4 + i) * 512 + col0 + (tx << 2)) = v;
    }
}

// ---------------- K2: per-feature sum / sumsq over 4096 rows (atomics) ----------------
__global__ __launch_bounds__(256) void k_stats(const float* __restrict__ q,
                                               float* __restrict__ stats) {
    const int t  = threadIdx.x;
    const int r0 = blockIdx.x * 64;
    float s0 = 0.f, q0 = 0.f, s1 = 0.f, q1 = 0.f;
    for (int r = 0; r < 64; ++r) {
        const float a = q[(r0 + r) * 512 + t];
        const float b = q[(r0 + r) * 512 + 256 + t];
        s0 += a; q0 += a * a;
        s1 += b; q1 += b * b;
    }
    atomicAdd(&stats[t], s0);
    atomicAdd(&stats[t + 256], s1);
    atomicAdd(&stats[512 + t], q0);
    atomicAdd(&stats[512 + t + 256], q1);
}

// ---------------- K2b: finalize mean / rstd ----------------
__global__ void k_finalize(const float* __restrict__ stats, float* __restrict__ mr) {
    const int f = threadIdx.x;   // 512 threads
    const float mean = stats[f] * (1.0f / 4096.0f);
    const float var  = stats[512 + f] * (1.0f / 4096.0f) - mean * mean;
    mr[f]       = mean;
    mr[512 + f] = rsqrtf(var + EPS);
}

// ---------------- K3: fused per-token PKM ----------------
__global__ __launch_bounds__(256) void k_pkm(
    const float* __restrict__ q,
    const float* __restrict__ mr,
    const float* __restrict__ gamma,
    const float* __restrict__ beta,
    const float* __restrict__ keys,
    const float* __restrict__ values,
    float* __restrict__ out)
{
    __shared__ float qn[512];
    __shared__ float sTopS[16][16];
    __shared__ int   sTopI[16][16];
    __shared__ float scTmp[8][16];
    __shared__ int   cpTmp[8][16];
    __shared__ float wW[128];
    __shared__ int   wI[128];

    const int tok  = blockIdx.x;
    const int tid  = threadIdx.x;
    const int lane = tid & 63;
    const int wave = tid >> 6;

    // normalize this token's q row: qn = (q - mean)*rstd*gamma + beta
    {
        const float v0 = q[tok * 512 + tid];
        const float v1 = q[tok * 512 + 256 + tid];
        qn[tid]       = (v0 - mr[tid]) * mr[512 + tid] * gamma[tid] + beta[tid];
        qn[tid + 256] = (v1 - mr[tid + 256]) * mr[512 + tid + 256] * gamma[tid + 256] + beta[tid + 256];
    }
    __syncthreads();

    // ---- phase 1: per-slice (h,p) dots vs 256 sub-keys + top-16 ----
    for (int sq = 0; sq < 4; ++sq) {
        const int s = wave * 4 + sq;     // slice id = h*2+p
        const int h = s >> 1;
        const int p = s & 1;
        float qv[32];
        #pragma unroll
        for (int d4 = 0; d4 < 8; ++d4) {
            const float4 t = *(const float4*)&qn[p * 256 + h * 32 + d4 * 4];
            qv[d4 * 4 + 0] = t.x; qv[d4 * 4 + 1] = t.y;
            qv[d4 * 4 + 2] = t.z; qv[d4 * 4 + 3] = t.w;
        }
        unsigned long long cand[4];
        #pragma unroll
        for (int j = 0; j < 4; ++j) {
            const int n = lane + 64 * j;
            const float4* kp4 = (const float4*)(keys + ((h * 256 + n) * 2 + p) * 32);
            float dot = 0.0f;
            #pragma unroll
            for (int d4 = 0; d4 < 8; ++d4) {
                const float4 kv = kp4[d4];
                dot += qv[d4 * 4 + 0] * kv.x + qv[d4 * 4 + 1] * kv.y
                     + qv[d4 * 4 + 2] * kv.z + qv[d4 * 4 + 3] * kv.w;
            }
            const unsigned int u  = __float_as_uint(dot);
            const unsigned int kb = (u & 0x80000000u) ? ~u : (u | 0x80000000u);
            cand[j] = ((unsigned long long)kb << 32) | (unsigned int)(255 - n);
        }
        for (int it = 0; it < 16; ++it) {
            unsigned long long m = cand[0];
            #pragma unroll
            for (int j = 1; j < 4; ++j) m = (cand[j] > m) ? cand[j] : m;
            #pragma unroll
            for (int off = 32; off > 0; off >>= 1) {
                const unsigned long long o = __shfl_xor(m, off);
                m = (o > m) ? o : m;
            }
            #pragma unroll
            for (int j = 0; j < 4; ++j) if (cand[j] == m) cand[j] = 0ULL;
            if (lane == 0) {
                const unsigned int kb = (unsigned int)(m >> 32);
                const unsigned int u  = (kb & 0x80000000u) ? (kb & 0x7FFFFFFFu) : ~kb;
                sTopS[s][it] = __uint_as_float(u);
                sTopI[s][it] = 255 - (int)(m & 0xFFu);
            }
        }
    }
    __syncthreads();

    // ---- phase 2a: combine (ha, ha+4 | same p) -> 256 candidates -> top-16 ----
    float mx0 = 0.f, ss0 = 0.f, mx1 = 0.f, ss1 = 0.f;
    #pragma unroll
    for (int r = 0; r < 2; ++r) {
        const int hh = wave * 2 + r;     // combined head = ha*2 + p
        const int ha = hh >> 1;
        const int p  = hh & 1;
        const int sa = ha * 2 + p;
        const int sb = (ha + 4) * 2 + p;
        const float sAv = sTopS[sa][lane >> 2];
        unsigned long long cand[4];
        #pragma unroll
        for (int j = 0; j < 4; ++j) {
            const int c = lane * 4 + j;          // 0..255, c = i*16 + jj
            const float sc = sAv + sTopS[sb][c & 15];
            const unsigned int u  = __float_as_uint(sc);
            const unsigned int kb = (u & 0x80000000u) ? ~u : (u | 0x80000000u);
            cand[j] = ((unsigned long long)kb << 32) | (unsigned int)(255 - c);
        }
        float mx = 0.0f, ssum = 0.0f;
        for (int it = 0; it < 16; ++it) {
            unsigned long long m = cand[0];
            #pragma unroll
            for (int j = 1; j < 4; ++j) m = (cand[j] > m) ? cand[j] : m;
            #pragma unroll
            for (int off = 32; off > 0; off >>= 1) {
                const unsigned long long o = __shfl_xor(m, off);
                m = (o > m) ? o : m;
            }
            #pragma unroll
            for (int j = 0; j < 4; ++j) if (cand[j] == m) cand[j] = 0ULL;
            const unsigned int kb = (unsigned int)(m >> 32);
            const unsigned int u  = (kb & 0x80000000u) ? (kb & 0x7FFFFFFFu) : ~kb;
            const float sc = __uint_as_float(u);
            const int   c  = 255 - (int)(m & 0xFFu);
            if (it == 0) mx = sc;          // first extraction is the max
            ssum += __expf(sc - mx);
            if (lane == 0) { scTmp[hh][it] = sc; cpTmp[hh][it] = c; }
        }
        if (r == 0) { mx0 = mx; ss0 = ssum; } else { mx1 = mx; ss1 = ssum; }
    }
    __syncthreads();

    // ---- phase 2b: softmax weights + value indices ----
    #pragma unroll
    for (int r = 0; r < 2; ++r) {
        const int hh = wave * 2 + r;
        const int ha = hh >> 1;
        const int p  = hh & 1;
        const int sa = ha * 2 + p;
        const int sb = (ha + 4) * 2 + p;
        const float mx   = (r == 0) ? mx0 : mx1;
        const float ssum = (r == 0) ? ss0 : ss1;
        if (lane < 16) {
            const float sc = scTmp[hh][lane];
            const int   c  = cpTmp[hh][lane];
            wW[hh * 16 + lane] = __expf(sc - mx) / ssum;
            wI[hh * 16 + lane] = sTopI[sa][c >> 4] * 256 + sTopI[sb][c & 15];
        }
    }
    __syncthreads();

    // ---- phase 3: weighted gather of 128 value rows ----
    float2 acc = make_float2(0.0f, 0.0f);
    const float2* vb = (const float2*)values;
    #pragma unroll 4
    for (int k = 0; k < 128; ++k) {
        const float w   = wW[k];
        const int   idx = wI[k];
        const float2 v  = vb[idx * 256 + tid];
        acc.x += w * v.x;
        acc.y += w * v.y;
    }
    *(float2*)(out + tok * 512 + tid * 2) = acc;
}

extern "C" void kernel_launch(void* const* d_in, const int* in_sizes, int n_in,
                              void* d_out, int out_size, void* d_ws, size_t ws_size,
                              hipStream_t stream) {
    const float* x      = (const float*)d_in[0];
    const float* Wq     = (const float*)d_in[1];
    const float* gamma  = (const float*)d_in[2];
    const float* beta   = (const float*)d_in[3];
    const float* keys   = (const float*)d_in[4];
    const float* values = (const float*)d_in[5];
    float* out = (float*)d_out;

    float* q     = (float*)d_ws;               // 4096*512 floats
    float* stats = q + NTOK * 512;             // 1024 floats (sum, sumsq)
    float* mr    = stats + 1024;               // 1024 floats (mean, rstd)

    k_zero<<<1, 1024, 0, stream>>>(stats);
    dim3 g1(NTOK / 64, 512 / 64);
    k_gemm<<<g1, 256, 0, stream>>>(x, Wq, q);
    k_stats<<<NTOK / 64, 256, 0, stream>>>(q, stats);
    k_finalize<<<1, 512, 0, stream>>>(stats, mr);
    k_pkm<<<NTOK, 256, 0, stream>>>(q, mr, gamma, beta, keys, values, out);
}